// Round 20
// baseline (253.901 us; speedup 1.0000x reference)
//
#include <hip/hip_runtime.h>

// LinearAttentionBlock bf16 MFMA. Attention reassociated: Q@(K'V); proj
// fused: x2 = x + Q@M + bp, M = (Wp@KtV^T)^T precomputed. QKV consumes fp32
// x directly. Final reduce: y = x2b + P0 + P1 + b2.
// FFN GEMMs (round-20): m97-reference 128x128/BK=32 tile, 4 waves, per-wave
// 64x64, 16KB LDS -> 3+ blocks/CU TLP, with the r8 toolchain applied:
//   asm ds_read_b128 (no hidden compiler vmcnt drains), counted lgkm(2/0),
//   2-way-free swizzle for 64B rows (granule ^= (row>>1)&3), LDS-transpose
//   epilogue with coalesced bf16x8 stores.
// FFN2: split-K=2 (1024 blocks) + fused reduce.

#define MROWS 8192
#define DMODEL 1024
#define DK 128
#define DFF 4096

typedef __attribute__((ext_vector_type(8))) __bf16 bf16x8;
typedef __attribute__((ext_vector_type(4))) float f32x4;

#define BAR()     __builtin_amdgcn_s_barrier()
#define WAITV(n)  asm volatile("s_waitcnt vmcnt(" #n ")" ::: "memory")
#define LGKMC(n)  asm volatile("s_waitcnt lgkmcnt(" #n ")" ::: "memory")
#define SCHED0()  __builtin_amdgcn_sched_barrier(0)
#define GLOAD(src, dst) __builtin_amdgcn_global_load_lds( \
    (const __attribute__((address_space(1))) void*)(src), \
    (__attribute__((address_space(3))) void*)(dst), 16, 0, 0)

#define LDSO(p) ((unsigned)(unsigned long long) \
    (__attribute__((address_space(3))) const char*)(const char*)(p))

__device__ __forceinline__ bf16x8 ldsr(unsigned off) {
    bf16x8 r;
    asm volatile("ds_read_b128 %0, %1" : "=v"(r) : "v"(off));
    return r;
}

__device__ __forceinline__ void cast_one(const float* s, __bf16* d, int i) {
    const float4 a = reinterpret_cast<const float4*>(s)[2 * i];
    const float4 b = reinterpret_cast<const float4*>(s)[2 * i + 1];
    bf16x8 o;
    o[0] = (__bf16)a.x; o[1] = (__bf16)a.y; o[2] = (__bf16)a.z; o[3] = (__bf16)a.w;
    o[4] = (__bf16)b.x; o[5] = (__bf16)b.y; o[6] = (__bf16)b.z; o[7] = (__bf16)b.w;
    reinterpret_cast<bf16x8*>(d)[i] = o;
}

// weight casts + bias pack in one launch; grid = 4353 blocks of 256
__global__ __launch_bounds__(256) void cast6b(
    const float* __restrict__ s0, __bf16* __restrict__ d0,
    const float* __restrict__ s1, __bf16* __restrict__ d1,
    const float* __restrict__ s2, __bf16* __restrict__ d2,
    const float* __restrict__ s3, __bf16* __restrict__ d3,
    const float* __restrict__ s4, __bf16* __restrict__ d4,
    const float* __restrict__ s5, __bf16* __restrict__ d5,
    const float* __restrict__ ba, const float* __restrict__ bb,
    const float* __restrict__ bc, float* __restrict__ bo)
{
    const int b = blockIdx.x, t = threadIdx.x;
    if      (b <  64)  cast_one(s0, d0, b * 256 + t);
    else if (b < 128)  cast_one(s1, d1, (b - 64) * 256 + t);
    else if (b < 192)  cast_one(s2, d2, (b - 128) * 256 + t);
    else if (b < 256)  cast_one(s3, d3, (b - 192) * 256 + t);
    else if (b < 2304) cast_one(s4, d4, (b - 256) * 256 + t);
    else if (b < 4352) cast_one(s5, d5, (b - 2304) * 256 + t);
    else if (t < 128) { bo[t] = ba[t]; bo[128 + t] = bb[t]; bo[256 + t] = bc[t]; }
}

// y = (float)x2b + P0 + P1 + b2   (y fp32 write-only)
__global__ __launch_bounds__(256) void ffn2_reduce2(
    float* __restrict__ y, const __bf16* __restrict__ x2b,
    const __bf16* __restrict__ P0, const __bf16* __restrict__ P1,
    const float* __restrict__ b2, int n8)
{
    for (int i = blockIdx.x * blockDim.x + threadIdx.x; i < n8;
         i += gridDim.x * blockDim.x) {
        const int col0 = (i << 3) & (DMODEL - 1);
        const float4 ba = *reinterpret_cast<const float4*>(&b2[col0]);
        const float4 bb = *reinterpret_cast<const float4*>(&b2[col0 + 4]);
        const bf16x8 xx = reinterpret_cast<const bf16x8*>(x2b)[i];
        const bf16x8 p0 = reinterpret_cast<const bf16x8*>(P0)[i];
        const bf16x8 p1 = reinterpret_cast<const bf16x8*>(P1)[i];
        float4 o0, o1;
        o0.x = (float)xx[0] + (float)p0[0] + (float)p1[0] + ba.x;
        o0.y = (float)xx[1] + (float)p0[1] + (float)p1[1] + ba.y;
        o0.z = (float)xx[2] + (float)p0[2] + (float)p1[2] + ba.z;
        o0.w = (float)xx[3] + (float)p0[3] + (float)p1[3] + ba.w;
        o1.x = (float)xx[4] + (float)p0[4] + (float)p1[4] + bb.x;
        o1.y = (float)xx[5] + (float)p0[5] + (float)p1[5] + bb.y;
        o1.z = (float)xx[6] + (float)p0[6] + (float)p1[6] + bb.z;
        o1.w = (float)xx[7] + (float)p0[7] + (float)p1[7] + bb.w;
        reinterpret_cast<float4*>(y)[2 * i]     = o0;
        reinterpret_cast<float4*>(y)[2 * i + 1] = o1;
    }
}

// ---------------------------------------------------------------------------
// 128x128 m97-style GEMM (small ops). F32A: fp32 A, reg-staged cast into LDS.
// ---------------------------------------------------------------------------
template<bool RELU, bool RESID, bool BIAS, bool OUTBF, bool DUAL, bool F32A>
__global__ __launch_bounds__(256) void gemm128(
    const void* __restrict__ Ap, int lda,
    const __bf16* __restrict__ W,
    const float* __restrict__ bias,
    const float* __restrict__ resid,
    void* __restrict__ Cout, __bf16* __restrict__ Cbf, int ldc, int K)
{
    constexpr int BK = 32;
    __shared__ __bf16 As[128 * BK];
    __shared__ __bf16 Bs[128 * BK];

    const int tid  = threadIdx.x;
    const int lane = tid & 63;
    const int w    = tid >> 6;
    const int wm   = w >> 1;
    const int wn   = w & 1;
    const int fr   = lane & 15;
    const int fq   = lane >> 4;

    const long row0 = (long)blockIdx.y * 128;
    const long col0 = (long)blockIdx.x * 128;

    const int sr = (w << 4) + (lane >> 2);
    const int sc = (lane & 3) << 3;

    const __bf16* gA0 = F32A ? nullptr : (const __bf16*)Ap + (row0 + sr) * (long)lda + sc;
    const __bf16* gA1 = F32A ? nullptr : (const __bf16*)Ap + (row0 + 64 + sr) * (long)lda + sc;
    const float*  gAf = F32A ? (const float*)Ap + (row0 + (tid >> 1)) * (long)lda
                               + ((tid & 1) << 4)
                             : nullptr;
    const __bf16* gW0 = W + (col0 + sr) * (long)K + sc;
    const __bf16* gW1 = W + (col0 + 64 + sr) * (long)K + sc;

    __bf16* lA0 = &As[(w << 4) * BK];
    __bf16* lA1 = &As[((w << 4) + 64) * BK];
    __bf16* lB0 = &Bs[(w << 4) * BK];
    __bf16* lB1 = &Bs[((w << 4) + 64) * BK];

    f32x4 acc[4][4] = {};

    for (int k0 = 0; k0 < K; k0 += BK) {
        if constexpr (F32A) {
            const float* s = gAf + k0;
            const float4 f0 = reinterpret_cast<const float4*>(s)[0];
            const float4 f1 = reinterpret_cast<const float4*>(s)[1];
            const float4 f2 = reinterpret_cast<const float4*>(s)[2];
            const float4 f3 = reinterpret_cast<const float4*>(s)[3];
            bf16x8 o0, o1;
            o0[0] = (__bf16)f0.x; o0[1] = (__bf16)f0.y; o0[2] = (__bf16)f0.z; o0[3] = (__bf16)f0.w;
            o0[4] = (__bf16)f1.x; o0[5] = (__bf16)f1.y; o0[6] = (__bf16)f1.z; o0[7] = (__bf16)f1.w;
            o1[0] = (__bf16)f2.x; o1[1] = (__bf16)f2.y; o1[2] = (__bf16)f2.z; o1[3] = (__bf16)f2.w;
            o1[4] = (__bf16)f3.x; o1[5] = (__bf16)f3.y; o1[6] = (__bf16)f3.z; o1[7] = (__bf16)f3.w;
            const int ar = tid >> 1, ac = (tid & 1) << 4;
            *reinterpret_cast<bf16x8*>(&As[ar * BK + ac])     = o0;
            *reinterpret_cast<bf16x8*>(&As[ar * BK + ac + 8]) = o1;
        } else {
            GLOAD(gA0 + k0, lA0);
            GLOAD(gA1 + k0, lA1);
        }
        GLOAD(gW0 + k0, lB0);
        GLOAD(gW1 + k0, lB1);
        __syncthreads();

        bf16x8 af[4], bfr[4];
        #pragma unroll
        for (int m = 0; m < 4; m++)
            af[m] = *reinterpret_cast<const bf16x8*>(
                &As[(wm * 64 + m * 16 + fr) * BK + fq * 8]);
        #pragma unroll
        for (int n = 0; n < 4; n++)
            bfr[n] = *reinterpret_cast<const bf16x8*>(
                &Bs[(wn * 64 + n * 16 + fr) * BK + fq * 8]);

        #pragma unroll
        for (int m = 0; m < 4; m++)
            #pragma unroll
            for (int n = 0; n < 4; n++)
                acc[m][n] = __builtin_amdgcn_mfma_f32_16x16x32_bf16(
                    af[m], bfr[n], acc[m][n], 0, 0, 0);
        __syncthreads();
    }

    float bc[4];
    #pragma unroll
    for (int n = 0; n < 4; n++)
        bc[n] = BIAS ? bias[col0 + wn * 64 + n * 16 + fr] : 0.0f;
    #pragma unroll
    for (int m = 0; m < 4; m++) {
        #pragma unroll
        for (int j = 0; j < 4; j++) {
            const long r = row0 + wm * 64 + m * 16 + fq * 4 + j;
            #pragma unroll
            for (int n = 0; n < 4; n++) {
                const long c = col0 + wn * 64 + n * 16 + fr;
                float v = acc[m][n][j] + bc[n];
                if constexpr (RESID) v += resid[r * ldc + c];
                if constexpr (RELU)  v = fmaxf(v, 0.0f);
                if constexpr (OUTBF) ((__bf16*)Cout)[r * ldc + c] = (__bf16)v;
                else                 ((float*)Cout)[r * ldc + c] = v;
                if constexpr (DUAL)  Cbf[r * ldc + c] = (__bf16)v;
            }
        }
    }
}

// ---------------------------------------------------------------------------
// FFN GEMM (round-20): 128x128 tile, 4 waves (2M x 2N), per-wave 64x64,
// BK=32, 16KB LDS (A[128x32]@0, B[128x32]@8192) -> 3+ blocks/CU.
// Per tile: 4 global_load_lds -> WAITV(0)+BAR -> 8 asm ds_read_b128
// (B n0-3, A m0-3) -> LGKMC(2) MFMA m0-1 -> LGKMC(0) MFMA m2-3 -> BAR.
// Swizzle (64B rows): granule g of row R holds global granule g^((R>>1)&3);
// staged via pre-swizzled source col ((lane&3)^((lane>>3)&3))*8; read at
// rb = fr*64 + ((fq^((fr>>1)&3))<<4) -> exact 2-way bank aliasing (free).
// Epilogue: per-wave 4KB LDS transpose (2 passes) -> coalesced bf16x8.
// Split-K: shard sid = bid/nb; out at sid*sstride. nb % 8 == 0.
// ---------------------------------------------------------------------------
template<bool RELU, bool BIAS>
__global__ __launch_bounds__(256, 3) void gemm_ffn128(
    const __bf16* __restrict__ A, int lda,
    const __bf16* __restrict__ W, int ldw,
    const float* __restrict__ bias,
    __bf16* __restrict__ Cout, long sstride, int ldc,
    int klen, int nb, int nbx)
{
    __shared__ char lds[16384];

    const int bid = blockIdx.x;
    const int sid = bid / nb;
    const int ib  = bid % nb;
    const int chunk = nb >> 3;
    const int swz   = (ib & 7) * chunk + (ib >> 3);
    const int bx    = swz % nbx;
    const int by    = swz / nbx;

    const long row0 = (long)by * 128;
    const long col0 = (long)bx * 128;

    const __bf16* Ash = A + (long)sid * klen;
    const __bf16* Wsh = W + (long)sid * klen;

    const int tid  = threadIdx.x;
    const int lane = tid & 63;
    const int w    = tid >> 6;
    const int wm   = w >> 1;
    const int wn   = w & 1;
    const int fr   = lane & 15;
    const int fq   = lane >> 4;

    // staging: row sr = w*16 + lane>>2 (0..63), pre-swizzled source granule
    const int sr = (w << 4) + (lane >> 2);
    const int sc = (((lane & 3) ^ ((lane >> 3) & 3)) << 3);
    const __bf16* gA0 = Ash + (row0 + sr) * (long)lda + sc;
    const __bf16* gA1 = Ash + (row0 + 64 + sr) * (long)lda + sc;
    const __bf16* gW0 = Wsh + (col0 + sr) * (long)ldw + sc;
    const __bf16* gW1 = Wsh + (col0 + 64 + sr) * (long)ldw + sc;

    char* ldsc = &lds[0];
    const unsigned lbase = LDSO(ldsc);
    const int nt = klen >> 5;

    char* lA0 = ldsc + (w << 10);
    char* lA1 = ldsc + 4096  + (w << 10);
    char* lB0 = ldsc + 8192  + (w << 10);
    char* lB1 = ldsc + 12288 + (w << 10);

    const unsigned rb = fr * 64 + ((fq ^ ((fr >> 1) & 3)) << 4);
    const unsigned pA = lbase + (wm << 12);            // A half: 64 rows = 4KB
    const unsigned pB = lbase + 8192 + (wn << 12);

    f32x4 acc[4][4] = {};
    bf16x8 af[4], bfr[4];

    for (int t = 0; t < nt; ++t) {
        const long k0 = (long)t * 32;
        GLOAD(gA0 + k0, lA0);
        GLOAD(gA1 + k0, lA1);
        GLOAD(gW0 + k0, lB0);
        GLOAD(gW1 + k0, lB1);
        WAITV(0);
        BAR();                          // tile t fully in LDS for all waves

        #pragma unroll
        for (int n = 0; n < 4; n++) bfr[n] = ldsr(pB + rb + n * 1024);
        #pragma unroll
        for (int m = 0; m < 4; m++) af[m]  = ldsr(pA + rb + m * 1024);

        LGKMC(2); SCHED0();             // B + A m0-1 landed
        __builtin_amdgcn_s_setprio(1);
        #pragma unroll
        for (int m = 0; m < 2; m++)
            #pragma unroll
            for (int n = 0; n < 4; n++)
                acc[m][n] = __builtin_amdgcn_mfma_f32_16x16x32_bf16(
                    af[m], bfr[n], acc[m][n], 0, 0, 0);
        __builtin_amdgcn_s_setprio(0);
        LGKMC(0); SCHED0();             // A m2-3 landed
        __builtin_amdgcn_s_setprio(1);
        #pragma unroll
        for (int m = 2; m < 4; m++)
            #pragma unroll
            for (int n = 0; n < 4; n++)
                acc[m][n] = __builtin_amdgcn_mfma_f32_16x16x32_bf16(
                    af[m], bfr[n], acc[m][n], 0, 0, 0);
        __builtin_amdgcn_s_setprio(0);

        BAR();                          // all reads done before next stage
    }

    // epilogue: per-wave 4KB LDS transpose (2 passes), coalesced bf16x8 stores
    __bf16* Cb = Cout + (long)sid * sstride;
    float bc[4];
    #pragma unroll
    for (int n = 0; n < 4; n++)
        bc[n] = BIAS ? bias[col0 + wn * 64 + n * 16 + fr] : 0.0f;

    __bf16* sw = reinterpret_cast<__bf16*>(ldsc) + (w << 11);  // 4KB/wave
    const long crow0 = row0 + wm * 64;
    const long ccol0 = col0 + wn * 64;
    #pragma unroll
    for (int pass = 0; pass < 2; pass++) {
        #pragma unroll
        for (int mi = 0; mi < 2; mi++) {
            const int m = pass * 2 + mi;
            #pragma unroll
            for (int j = 0; j < 4; j++) {
                const int row = mi * 16 + fq * 4 + j;    // 0..31
                #pragma unroll
                for (int n = 0; n < 4; n++) {
                    float v = acc[m][n][j] + bc[n];
                    if constexpr (RELU) v = fmaxf(v, 0.0f);
                    sw[row * 64 + n * 16 + fr] = (__bf16)v;
                }
            }
        }
        #pragma unroll
        for (int i = 0; i < 4; i++) {
            const bf16x8 vv = *reinterpret_cast<const bf16x8*>(sw + i * 512 + lane * 8);
            const int r  = pass * 32 + i * 8 + (lane >> 3);
            const int cg = (lane & 7) << 3;
            *reinterpret_cast<bf16x8*>(&Cb[(crow0 + r) * (long)ldc + ccol0 + cg]) = vv;
        }
        __builtin_amdgcn_s_waitcnt(0);  // drain before next pass overwrites
    }
}

// ---------------------------------------------------------------------------
// K^T @ V partials + reduce (row-major KtV for the M-fusion)
// ---------------------------------------------------------------------------
__global__ __launch_bounds__(256) void ktv_partial(
    const __bf16* __restrict__ Kp, const __bf16* __restrict__ Vp,
    int ld, float* __restrict__ part)
{
    __shared__ float ks[32][DK];
    __shared__ float vs[32][DK];
    const int tid = threadIdx.x;
    const int ti  = tid >> 4;
    const int tj  = tid & 15;
    float acc[8][8] = {};
    const long base = (long)blockIdx.x * 128;

    for (int n0 = 0; n0 < 128; n0 += 32) {
        for (int t = tid; t < 512; t += 256) {
            const int r  = t >> 4;
            const int cc = (t & 15) << 3;
            const bf16x8 k8 = *reinterpret_cast<const bf16x8*>(
                &Kp[(base + n0 + r) * (long)ld + cc]);
            const bf16x8 v8 = *reinterpret_cast<const bf16x8*>(
                &Vp[(base + n0 + r) * (long)ld + cc]);
            #pragma unroll
            for (int u = 0; u < 8; u++) {
                ks[r][cc + u] = (float)k8[u];
                vs[r][cc + u] = (float)v8[u];
            }
        }
        __syncthreads();
        for (int n = 0; n < 32; n++) {
            float kk[8], vv[8];
            #pragma unroll
            for (int i = 0; i < 8; i++) kk[i] = ks[n][(ti << 3) + i];
            #pragma unroll
            for (int j = 0; j < 8; j++) vv[j] = vs[n][(tj << 3) + j];
            #pragma unroll
            for (int i = 0; i < 8; i++)
                #pragma unroll
                for (int j = 0; j < 8; j++)
                    acc[i][j] = fmaf(kk[i], vv[j], acc[i][j]);
        }
        __syncthreads();
    }

    float* dst = &part[(long)blockIdx.x * (DK * DK)];
    #pragma unroll
    for (int i = 0; i < 8; i++) {
        const int ig = (ti << 3) + i;
        *reinterpret_cast<float4*>(&dst[ig * DK + (tj << 3)]) =
            make_float4(acc[i][0], acc[i][1], acc[i][2], acc[i][3]);
        *reinterpret_cast<float4*>(&dst[ig * DK + (tj << 3) + 4]) =
            make_float4(acc[i][4], acc[i][5], acc[i][6], acc[i][7]);
    }
}

__global__ __launch_bounds__(256) void ktv_reduce(
    const float* __restrict__ part, __bf16* __restrict__ ktvR)
{
    const int t = blockIdx.x * 256 + threadIdx.x;   // row-major KtV[i][j]
    float s = 0.0f;
    for (int b = 0; b < 64; b++) s += part[(long)b * (DK * DK) + t];
    ktvR[t] = (__bf16)s;
}

// ---------------------------------------------------------------------------
extern "C" void kernel_launch(void* const* d_in, const int* in_sizes, int n_in,
                              void* d_out, int out_size, void* d_ws, size_t ws_size,
                              hipStream_t stream) {
    const float* x  = (const float*)d_in[0];
    const float* Wq = (const float*)d_in[1];
    const float* bq = (const float*)d_in[2];
    const float* Wk = (const float*)d_in[3];
    const float* bk = (const float*)d_in[4];
    const float* Wv = (const float*)d_in[5];
    const float* bv = (const float*)d_in[6];
    const float* Wp = (const float*)d_in[7];
    const float* bp = (const float*)d_in[8];
    const float* W1 = (const float*)d_in[9];
    const float* b1 = (const float*)d_in[10];
    const float* W2 = (const float*)d_in[11];
    const float* b2 = (const float*)d_in[12];
    float* out = (float*)d_out;

    char* ws = (char*)d_ws;
    const size_t MB = 1ull << 20;
    __bf16* P0b   = (__bf16*)(ws);              // shard-0 partial (16 MiB)
    __bf16* P1b   = P0b + (long)MROWS * DMODEL; // shard-1 partial (ws+16MiB)
    __bf16* x2b   = (__bf16*)(ws +  34 * MB);   // 16 MiB (live thru reduce)
    __bf16* Hb    = (__bf16*)(ws +  51 * MB);   // 64 MiB
    __bf16* QKVb  = (__bf16*)(ws + 119 * MB);   //  6.3 MB [8192][384]
    __bf16* W1b   = (__bf16*)(ws + 126 * MB);   //  8.4 MB
    __bf16* W2b   = (__bf16*)(ws + 135 * MB);   //  8.4 MB
    __bf16* Wqkvb = (__bf16*)(ws + 144 * MB);   //  0.8 MB [384][1024]
    __bf16* Wpb   = (__bf16*)(ws + 145 * MB);   //  0.3 MB
    float*  Part  = (float*) (ws + 146 * MB);   //  4.2 MB
    __bf16* KtvRb = (__bf16*)(ws + 151 * MB);   //  32 KB (row-major KtV)
    __bf16* MtB   = (__bf16*)(ws + 152 * MB);   //  256 KB (M^T = Wp@KtV^T)
    float*  bqkvf = (float*) (ws + 155 * MB);   //  1.5 KB

    const dim3 blk(256);

    // weight casts + bias pack, one launch
    cast6b<<<4353, blk, 0, stream>>>(
        Wq, Wqkvb, Wk, Wqkvb + DK * DMODEL, Wv, Wqkvb + 2 * DK * DMODEL,
        Wp, Wpb, W1, W1b, W2, W2b, bq, bk, bv, bqkvf);

    // QKV packed projection from fp32 x (fused cast) -> bf16 [8192,384]
    gemm128<false,false,true,true,false,true><<<dim3(3, 64), blk, 0, stream>>>(
        x, DMODEL, Wqkvb, bqkvf, nullptr, QKVb, nullptr, 3 * DK, DMODEL);

    // KtV (128x128) -> row-major bf16
    ktv_partial<<<64, blk, 0, stream>>>(QKVb + DK, QKVb + 2 * DK, 3 * DK, Part);
    ktv_reduce <<<64, blk, 0, stream>>>(Part, KtvRb);

    // M^T[n][k] = sum_d Wp[n][d]*KtV[k][d] -> bf16 [1024][128]
    gemm128<false,false,false,true,false,false><<<dim3(1, 8), blk, 0, stream>>>(
        Wpb, DK, KtvRb, nullptr, nullptr, MtB, nullptr, DK, DK);

    // x2 = x + Q @ M + bp -> bf16 x2b ONLY
    gemm128<false,true,true,true,false,false><<<dim3(8, 64), blk, 0, stream>>>(
        QKVb, 3 * DK, MtB, bp, x, x2b, nullptr, DMODEL, DK);

    // h = relu(x2 @ W1^T + b1) -> bf16 [8192,4096]
    // grid = (4096/128) x (8192/128) = 32 x 64 = 2048 blocks, 3+/CU; nt=32
    gemm_ffn128<true,true><<<2048, blk, 0, stream>>>(
        x2b, DMODEL, W1b, DMODEL, b1, Hb, 0, DFF, DMODEL, 2048, DFF / 128);

    // FFN2 split-K=2 -> bf16 partials P0,P1
    // grid = 2 x (8 x 64) = 1024 blocks; klen = 2048, nt = 64
    gemm_ffn128<false,false><<<1024, blk, 0, stream>>>(
        Hb, DFF, W2b, DFF, nullptr, P0b,
        (long)MROWS * DMODEL, DMODEL, DFF / 2, 512, DMODEL / 128);

    // y = x2b + P0 + P1 + b2 (write-only fp32 d_out)
    ffn2_reduce2<<<2048, blk, 0, stream>>>(out, x2b, P0b, P1b, b2,
                                           MROWS * DMODEL / 8);
}

// Round 21
// 221.501 us; speedup vs baseline: 1.1463x; 1.1463x over previous
//
#include <hip/hip_runtime.h>

// LinearAttentionBlock bf16 MFMA — FINAL (round-19 configuration, 221.6 µs).
// Attention reassociated: Q@(K'V); proj fused: x2 = x + Q@M + bp with
// M = (Wp@KtV^T)^T precomputed. QKV consumes fp32 x directly (fused cast).
// Final reduce: y = x2b + P0 + P1 + b2 (write-only).
// FFN GEMMs: 256x128/BK=64, single 48KB LDS, 2 blocks/CU TLP, drain
// schedule with counted lgkm(12/8/4/0), T2 XOR swizzle.
// FFN2: split-K=2 (512 blocks). Structure space exhausted (r9-r20 ablations);
// this is the verified local optimum.

#define MROWS 8192
#define DMODEL 1024
#define DK 128
#define DFF 4096

typedef __attribute__((ext_vector_type(8))) __bf16 bf16x8;
typedef __attribute__((ext_vector_type(4))) float f32x4;

#define BAR()     __builtin_amdgcn_s_barrier()
#define WAITV(n)  asm volatile("s_waitcnt vmcnt(" #n ")" ::: "memory")
#define LGKMC(n)  asm volatile("s_waitcnt lgkmcnt(" #n ")" ::: "memory")
#define SCHED0()  __builtin_amdgcn_sched_barrier(0)
#define GLOAD(src, dst) __builtin_amdgcn_global_load_lds( \
    (const __attribute__((address_space(1))) void*)(src), \
    (__attribute__((address_space(3))) void*)(dst), 16, 0, 0)

#define LDSO(p) ((unsigned)(unsigned long long) \
    (__attribute__((address_space(3))) const char*)(const char*)(p))

__device__ __forceinline__ bf16x8 ldsr(unsigned off) {
    bf16x8 r;
    asm volatile("ds_read_b128 %0, %1" : "=v"(r) : "v"(off));
    return r;
}

__device__ __forceinline__ void cast_one(const float* s, __bf16* d, int i) {
    const float4 a = reinterpret_cast<const float4*>(s)[2 * i];
    const float4 b = reinterpret_cast<const float4*>(s)[2 * i + 1];
    bf16x8 o;
    o[0] = (__bf16)a.x; o[1] = (__bf16)a.y; o[2] = (__bf16)a.z; o[3] = (__bf16)a.w;
    o[4] = (__bf16)b.x; o[5] = (__bf16)b.y; o[6] = (__bf16)b.z; o[7] = (__bf16)b.w;
    reinterpret_cast<bf16x8*>(d)[i] = o;
}

// weight casts + bias pack in one launch; grid = 4353 blocks of 256
__global__ __launch_bounds__(256) void cast6b(
    const float* __restrict__ s0, __bf16* __restrict__ d0,
    const float* __restrict__ s1, __bf16* __restrict__ d1,
    const float* __restrict__ s2, __bf16* __restrict__ d2,
    const float* __restrict__ s3, __bf16* __restrict__ d3,
    const float* __restrict__ s4, __bf16* __restrict__ d4,
    const float* __restrict__ s5, __bf16* __restrict__ d5,
    const float* __restrict__ ba, const float* __restrict__ bb,
    const float* __restrict__ bc, float* __restrict__ bo)
{
    const int b = blockIdx.x, t = threadIdx.x;
    if      (b <  64)  cast_one(s0, d0, b * 256 + t);
    else if (b < 128)  cast_one(s1, d1, (b - 64) * 256 + t);
    else if (b < 192)  cast_one(s2, d2, (b - 128) * 256 + t);
    else if (b < 256)  cast_one(s3, d3, (b - 192) * 256 + t);
    else if (b < 2304) cast_one(s4, d4, (b - 256) * 256 + t);
    else if (b < 4352) cast_one(s5, d5, (b - 2304) * 256 + t);
    else if (t < 128) { bo[t] = ba[t]; bo[128 + t] = bb[t]; bo[256 + t] = bc[t]; }
}

// y = (float)x2b + P0 + P1 + b2   (y fp32 write-only)
__global__ __launch_bounds__(256) void ffn2_reduce2(
    float* __restrict__ y, const __bf16* __restrict__ x2b,
    const __bf16* __restrict__ P0, const __bf16* __restrict__ P1,
    const float* __restrict__ b2, int n8)
{
    for (int i = blockIdx.x * blockDim.x + threadIdx.x; i < n8;
         i += gridDim.x * blockDim.x) {
        const int col0 = (i << 3) & (DMODEL - 1);
        const float4 ba = *reinterpret_cast<const float4*>(&b2[col0]);
        const float4 bb = *reinterpret_cast<const float4*>(&b2[col0 + 4]);
        const bf16x8 xx = reinterpret_cast<const bf16x8*>(x2b)[i];
        const bf16x8 p0 = reinterpret_cast<const bf16x8*>(P0)[i];
        const bf16x8 p1 = reinterpret_cast<const bf16x8*>(P1)[i];
        float4 o0, o1;
        o0.x = (float)xx[0] + (float)p0[0] + (float)p1[0] + ba.x;
        o0.y = (float)xx[1] + (float)p0[1] + (float)p1[1] + ba.y;
        o0.z = (float)xx[2] + (float)p0[2] + (float)p1[2] + ba.z;
        o0.w = (float)xx[3] + (float)p0[3] + (float)p1[3] + ba.w;
        o1.x = (float)xx[4] + (float)p0[4] + (float)p1[4] + bb.x;
        o1.y = (float)xx[5] + (float)p0[5] + (float)p1[5] + bb.y;
        o1.z = (float)xx[6] + (float)p0[6] + (float)p1[6] + bb.z;
        o1.w = (float)xx[7] + (float)p0[7] + (float)p1[7] + bb.w;
        reinterpret_cast<float4*>(y)[2 * i]     = o0;
        reinterpret_cast<float4*>(y)[2 * i + 1] = o1;
    }
}

// ---------------------------------------------------------------------------
// 128x128 m97-style GEMM. F32A: A source is fp32, reg-staged cast into LDS.
// ---------------------------------------------------------------------------
template<bool RELU, bool RESID, bool BIAS, bool OUTBF, bool DUAL, bool F32A>
__global__ __launch_bounds__(256) void gemm128(
    const void* __restrict__ Ap, int lda,
    const __bf16* __restrict__ W,
    const float* __restrict__ bias,
    const float* __restrict__ resid,
    void* __restrict__ Cout, __bf16* __restrict__ Cbf, int ldc, int K)
{
    constexpr int BK = 32;
    __shared__ __bf16 As[128 * BK];
    __shared__ __bf16 Bs[128 * BK];

    const int tid  = threadIdx.x;
    const int lane = tid & 63;
    const int w    = tid >> 6;
    const int wm   = w >> 1;
    const int wn   = w & 1;
    const int fr   = lane & 15;
    const int fq   = lane >> 4;

    const long row0 = (long)blockIdx.y * 128;
    const long col0 = (long)blockIdx.x * 128;

    const int sr = (w << 4) + (lane >> 2);
    const int sc = (lane & 3) << 3;

    const __bf16* gA0 = F32A ? nullptr : (const __bf16*)Ap + (row0 + sr) * (long)lda + sc;
    const __bf16* gA1 = F32A ? nullptr : (const __bf16*)Ap + (row0 + 64 + sr) * (long)lda + sc;
    const float*  gAf = F32A ? (const float*)Ap + (row0 + (tid >> 1)) * (long)lda
                               + ((tid & 1) << 4)
                             : nullptr;
    const __bf16* gW0 = W + (col0 + sr) * (long)K + sc;
    const __bf16* gW1 = W + (col0 + 64 + sr) * (long)K + sc;

    __bf16* lA0 = &As[(w << 4) * BK];
    __bf16* lA1 = &As[((w << 4) + 64) * BK];
    __bf16* lB0 = &Bs[(w << 4) * BK];
    __bf16* lB1 = &Bs[((w << 4) + 64) * BK];

    f32x4 acc[4][4] = {};

    for (int k0 = 0; k0 < K; k0 += BK) {
        if constexpr (F32A) {
            const float* s = gAf + k0;
            const float4 f0 = reinterpret_cast<const float4*>(s)[0];
            const float4 f1 = reinterpret_cast<const float4*>(s)[1];
            const float4 f2 = reinterpret_cast<const float4*>(s)[2];
            const float4 f3 = reinterpret_cast<const float4*>(s)[3];
            bf16x8 o0, o1;
            o0[0] = (__bf16)f0.x; o0[1] = (__bf16)f0.y; o0[2] = (__bf16)f0.z; o0[3] = (__bf16)f0.w;
            o0[4] = (__bf16)f1.x; o0[5] = (__bf16)f1.y; o0[6] = (__bf16)f1.z; o0[7] = (__bf16)f1.w;
            o1[0] = (__bf16)f2.x; o1[1] = (__bf16)f2.y; o1[2] = (__bf16)f2.z; o1[3] = (__bf16)f2.w;
            o1[4] = (__bf16)f3.x; o1[5] = (__bf16)f3.y; o1[6] = (__bf16)f3.z; o1[7] = (__bf16)f3.w;
            const int ar = tid >> 1, ac = (tid & 1) << 4;
            *reinterpret_cast<bf16x8*>(&As[ar * BK + ac])     = o0;
            *reinterpret_cast<bf16x8*>(&As[ar * BK + ac + 8]) = o1;
        } else {
            GLOAD(gA0 + k0, lA0);
            GLOAD(gA1 + k0, lA1);
        }
        GLOAD(gW0 + k0, lB0);
        GLOAD(gW1 + k0, lB1);
        __syncthreads();

        bf16x8 af[4], bfr[4];
        #pragma unroll
        for (int m = 0; m < 4; m++)
            af[m] = *reinterpret_cast<const bf16x8*>(
                &As[(wm * 64 + m * 16 + fr) * BK + fq * 8]);
        #pragma unroll
        for (int n = 0; n < 4; n++)
            bfr[n] = *reinterpret_cast<const bf16x8*>(
                &Bs[(wn * 64 + n * 16 + fr) * BK + fq * 8]);

        #pragma unroll
        for (int m = 0; m < 4; m++)
            #pragma unroll
            for (int n = 0; n < 4; n++)
                acc[m][n] = __builtin_amdgcn_mfma_f32_16x16x32_bf16(
                    af[m], bfr[n], acc[m][n], 0, 0, 0);
        __syncthreads();
    }

    float bc[4];
    #pragma unroll
    for (int n = 0; n < 4; n++)
        bc[n] = BIAS ? bias[col0 + wn * 64 + n * 16 + fr] : 0.0f;
    #pragma unroll
    for (int m = 0; m < 4; m++) {
        #pragma unroll
        for (int j = 0; j < 4; j++) {
            const long r = row0 + wm * 64 + m * 16 + fq * 4 + j;
            #pragma unroll
            for (int n = 0; n < 4; n++) {
                const long c = col0 + wn * 64 + n * 16 + fr;
                float v = acc[m][n][j] + bc[n];
                if constexpr (RESID) v += resid[r * ldc + c];
                if constexpr (RELU)  v = fmaxf(v, 0.0f);
                if constexpr (OUTBF) ((__bf16*)Cout)[r * ldc + c] = (__bf16)v;
                else                 ((float*)Cout)[r * ldc + c] = v;
                if constexpr (DUAL)  Cbf[r * ldc + c] = (__bf16)v;
            }
        }
    }
}

// ---------------------------------------------------------------------------
// FFN GEMM (r14-proven): 256x128 tile, 4 waves (2M x 2N), per-wave 128x64,
// BK=64. LDS: single buffer, A[256x64]@0 (32KB), B[128x64]@32768 (16KB).
// Drain loop: stage(12 global_load_lds) -> vmcnt(0)+BAR -> 24 asm ds_read
// + counted lgkm(12/8/4/0) + 4 MFMA clusters -> BAR. T2 swizzle. 2 blk/CU.
// ---------------------------------------------------------------------------
#define RD_B()                                             \
    _Pragma("unroll")                                      \
    for (int n = 0; n < 4; n++) {                          \
        bb[n][0] = ldsr(pB + rb0 + n * 2048);              \
        bb[n][1] = ldsr(pB + rb1 + n * 2048);              \
    }
#define RD_A(m0_, cnt_)                                    \
    _Pragma("unroll")                                      \
    for (int m = m0_; m < m0_ + cnt_; m++) {               \
        a[m][0] = ldsr(pA + rb0 + m * 2048);               \
        a[m][1] = ldsr(pA + rb1 + m * 2048);               \
    }
#define MFMA2(m0_)                                                            \
    _Pragma("unroll")                                                         \
    for (int m = m0_; m < m0_ + 2; m++)                                       \
        _Pragma("unroll")                                                     \
        for (int n = 0; n < 4; n++) {                                         \
            acc[m][n] = __builtin_amdgcn_mfma_f32_16x16x32_bf16(              \
                a[m][0], bb[n][0], acc[m][n], 0, 0, 0);                       \
            acc[m][n] = __builtin_amdgcn_mfma_f32_16x16x32_bf16(              \
                a[m][1], bb[n][1], acc[m][n], 0, 0, 0);                       \
        }

template<bool RELU, bool BIAS>
__global__ __launch_bounds__(256, 2) void gemm256x128(
    const __bf16* __restrict__ A, int lda,
    const __bf16* __restrict__ W, int ldw,
    const float* __restrict__ bias,
    __bf16* __restrict__ Cout, long sstride, int ldc,
    int klen, int nb, int nbx)
{
    __shared__ char lds[49152];

    const int bid = blockIdx.x;
    const int sid = bid / nb;
    const int ib  = bid % nb;
    const int chunk = nb >> 3;          // nb % 8 == 0
    const int swz   = (ib & 7) * chunk + (ib >> 3);
    const int bx    = swz % nbx;
    const int by    = swz / nbx;

    const long row0 = (long)by * 256;
    const long col0 = (long)bx * 128;

    const __bf16* Ash = A + (long)sid * klen;
    const __bf16* Wsh = W + (long)sid * klen;

    const int tid  = threadIdx.x;
    const int lane = tid & 63;
    const int w    = tid >> 6;     // 0..3
    const int wm   = w >> 1;       // A half (128 rows)
    const int wn   = w & 1;        // B half (64 cols)
    const int fr   = lane & 15;
    const int fq   = lane >> 4;

    const int scole = ((lane & 7) ^ (lane >> 3)) << 3;   // T2 pre-swizzled col
    const __bf16* gA = Ash + (row0 + w * 8 + (lane >> 3)) * (long)lda + scole;
    const __bf16* gB = Wsh + (col0 + w * 8 + (lane >> 3)) * (long)ldw + scole;

    char* ldsc = &lds[0];
    const unsigned lbase = LDSO(ldsc);
    const int nt = klen >> 6;

    auto stage = [&](int t) {
        const __bf16* ap = gA + (long)t * 64;
        const __bf16* bp = gB + (long)t * 64;
        #pragma unroll
        for (int r = 0; r < 8; r++)
            GLOAD(ap + (long)(32 * r) * lda, ldsc + r * 4096 + (w << 10));
        #pragma unroll
        for (int r = 0; r < 4; r++)
            GLOAD(bp + (long)(32 * r) * ldw, ldsc + 32768 + r * 4096 + (w << 10));
    };

    const unsigned rb0 = fr * 128 + ((fq * 16) ^ ((fr & 7) << 4));
    const unsigned rb1 = fr * 128 + ((64 + fq * 16) ^ ((fr & 7) << 4));
    const unsigned pA = lbase + (wm << 14);            // 16KB half of A
    const unsigned pB = lbase + 32768 + (wn << 13);    // 8KB half of B

    f32x4 acc[8][4] = {};
    bf16x8 a[8][2], bb[4][2];

    for (int t = 0; t < nt; ++t) {
        stage(t);
        WAITV(0);
        BAR();                 // tile t fully in LDS for all waves

        RD_B();                // 8 reads
        RD_A(0, 8);            // 16 reads

        LGKMC(12); SCHED0();
        __builtin_amdgcn_s_setprio(1); MFMA2(0); __builtin_amdgcn_s_setprio(0);
        LGKMC(8); SCHED0();
        __builtin_amdgcn_s_setprio(1); MFMA2(2); __builtin_amdgcn_s_setprio(0);
        LGKMC(4); SCHED0();
        __builtin_amdgcn_s_setprio(1); MFMA2(4); __builtin_amdgcn_s_setprio(0);
        LGKMC(0); SCHED0();
        __builtin_amdgcn_s_setprio(1); MFMA2(6); __builtin_amdgcn_s_setprio(0);

        BAR();                 // all reads done before next stage overwrites
    }

    // epilogue: per-wave 8KB LDS transpose (2 passes), coalesced bf16x8 stores
    __bf16* Cb = Cout + (long)sid * sstride;
    float bc[4];
    #pragma unroll
    for (int n = 0; n < 4; n++)
        bc[n] = BIAS ? bias[col0 + wn * 64 + n * 16 + fr] : 0.0f;

    __bf16* sw = reinterpret_cast<__bf16*>(ldsc) + (w << 12);  // 8KB/wave
    const long crow0 = row0 + wm * 128;
    const long ccol0 = col0 + wn * 64;
    #pragma unroll
    for (int half = 0; half < 2; half++) {
        #pragma unroll
        for (int m = 0; m < 4; m++)
            #pragma unroll
            for (int j = 0; j < 4; j++) {
                const int row = m * 16 + fq * 4 + j;     // 0..63
                #pragma unroll
                for (int n = 0; n < 4; n++) {
                    float v = acc[half * 4 + m][n][j] + bc[n];
                    if constexpr (RELU) v = fmaxf(v, 0.0f);
                    sw[row * 64 + n * 16 + fr] = (__bf16)v;
                }
            }
        #pragma unroll
        for (int i = 0; i < 8; i++) {
            const bf16x8 vv = *reinterpret_cast<const bf16x8*>(sw + i * 512 + lane * 8);
            const int r  = half * 64 + i * 8 + (lane >> 3);
            const int cg = (lane & 7) << 3;
            *reinterpret_cast<bf16x8*>(&Cb[(crow0 + r) * (long)ldc + ccol0 + cg]) = vv;
        }
        __builtin_amdgcn_s_waitcnt(0);  // drain lgkm before reusing slot
    }
}

// ---------------------------------------------------------------------------
// K^T @ V partials + reduce (row-major KtV for the M-fusion)
// ---------------------------------------------------------------------------
__global__ __launch_bounds__(256) void ktv_partial(
    const __bf16* __restrict__ Kp, const __bf16* __restrict__ Vp,
    int ld, float* __restrict__ part)
{
    __shared__ float ks[32][DK];
    __shared__ float vs[32][DK];
    const int tid = threadIdx.x;
    const int ti  = tid >> 4;
    const int tj  = tid & 15;
    float acc[8][8] = {};
    const long base = (long)blockIdx.x * 128;

    for (int n0 = 0; n0 < 128; n0 += 32) {
        for (int t = tid; t < 512; t += 256) {
            const int r  = t >> 4;
            const int cc = (t & 15) << 3;
            const bf16x8 k8 = *reinterpret_cast<const bf16x8*>(
                &Kp[(base + n0 + r) * (long)ld + cc]);
            const bf16x8 v8 = *reinterpret_cast<const bf16x8*>(
                &Vp[(base + n0 + r) * (long)ld + cc]);
            #pragma unroll
            for (int u = 0; u < 8; u++) {
                ks[r][cc + u] = (float)k8[u];
                vs[r][cc + u] = (float)v8[u];
            }
        }
        __syncthreads();
        for (int n = 0; n < 32; n++) {
            float kk[8], vv[8];
            #pragma unroll
            for (int i = 0; i < 8; i++) kk[i] = ks[n][(ti << 3) + i];
            #pragma unroll
            for (int j = 0; j < 8; j++) vv[j] = vs[n][(tj << 3) + j];
            #pragma unroll
            for (int i = 0; i < 8; i++)
                #pragma unroll
                for (int j = 0; j < 8; j++)
                    acc[i][j] = fmaf(kk[i], vv[j], acc[i][j]);
        }
        __syncthreads();
    }

    float* dst = &part[(long)blockIdx.x * (DK * DK)];
    #pragma unroll
    for (int i = 0; i < 8; i++) {
        const int ig = (ti << 3) + i;
        *reinterpret_cast<float4*>(&dst[ig * DK + (tj << 3)]) =
            make_float4(acc[i][0], acc[i][1], acc[i][2], acc[i][3]);
        *reinterpret_cast<float4*>(&dst[ig * DK + (tj << 3) + 4]) =
            make_float4(acc[i][4], acc[i][5], acc[i][6], acc[i][7]);
    }
}

__global__ __launch_bounds__(256) void ktv_reduce(
    const float* __restrict__ part, __bf16* __restrict__ ktvR)
{
    const int t = blockIdx.x * 256 + threadIdx.x;   // row-major KtV[i][j]
    float s = 0.0f;
    for (int b = 0; b < 64; b++) s += part[(long)b * (DK * DK) + t];
    ktvR[t] = (__bf16)s;
}

// ---------------------------------------------------------------------------
extern "C" void kernel_launch(void* const* d_in, const int* in_sizes, int n_in,
                              void* d_out, int out_size, void* d_ws, size_t ws_size,
                              hipStream_t stream) {
    const float* x  = (const float*)d_in[0];
    const float* Wq = (const float*)d_in[1];
    const float* bq = (const float*)d_in[2];
    const float* Wk = (const float*)d_in[3];
    const float* bk = (const float*)d_in[4];
    const float* Wv = (const float*)d_in[5];
    const float* bv = (const float*)d_in[6];
    const float* Wp = (const float*)d_in[7];
    const float* bp = (const float*)d_in[8];
    const float* W1 = (const float*)d_in[9];
    const float* b1 = (const float*)d_in[10];
    const float* W2 = (const float*)d_in[11];
    const float* b2 = (const float*)d_in[12];
    float* out = (float*)d_out;

    char* ws = (char*)d_ws;
    const size_t MB = 1ull << 20;
    __bf16* P0b   = (__bf16*)(ws);              // shard-0 partial (16 MiB)
    __bf16* P1b   = P0b + (long)MROWS * DMODEL; // shard-1 partial (ws+16MiB)
    __bf16* x2b   = (__bf16*)(ws +  34 * MB);   // 16 MiB (live thru reduce)
    __bf16* Hb    = (__bf16*)(ws +  51 * MB);   // 64 MiB
    __bf16* QKVb  = (__bf16*)(ws + 119 * MB);   //  6.3 MB [8192][384]
    __bf16* W1b   = (__bf16*)(ws + 126 * MB);   //  8.4 MB
    __bf16* W2b   = (__bf16*)(ws + 135 * MB);   //  8.4 MB
    __bf16* Wqkvb = (__bf16*)(ws + 144 * MB);   //  0.8 MB [384][1024]
    __bf16* Wpb   = (__bf16*)(ws + 145 * MB);   //  0.3 MB
    float*  Part  = (float*) (ws + 146 * MB);   //  4.2 MB
    __bf16* KtvRb = (__bf16*)(ws + 151 * MB);   //  32 KB (row-major KtV)
    __bf16* MtB   = (__bf16*)(ws + 152 * MB);   //  256 KB (M^T = Wp@KtV^T)
    float*  bqkvf = (float*) (ws + 155 * MB);   //  1.5 KB

    const dim3 blk(256);

    // weight casts + bias pack, one launch
    cast6b<<<4353, blk, 0, stream>>>(
        Wq, Wqkvb, Wk, Wqkvb + DK * DMODEL, Wv, Wqkvb + 2 * DK * DMODEL,
        Wp, Wpb, W1, W1b, W2, W2b, bq, bk, bv, bqkvf);

    // QKV packed projection from fp32 x (fused cast) -> bf16 [8192,384]
    gemm128<false,false,true,true,false,true><<<dim3(3, 64), blk, 0, stream>>>(
        x, DMODEL, Wqkvb, bqkvf, nullptr, QKVb, nullptr, 3 * DK, DMODEL);

    // KtV (128x128) -> row-major bf16
    ktv_partial<<<64, blk, 0, stream>>>(QKVb + DK, QKVb + 2 * DK, 3 * DK, Part);
    ktv_reduce <<<64, blk, 0, stream>>>(Part, KtvRb);

    // M^T[n][k] = sum_d Wp[n][d]*KtV[k][d] -> bf16 [1024][128]
    gemm128<false,false,false,true,false,false><<<dim3(1, 8), blk, 0, stream>>>(
        Wpb, DK, KtvRb, nullptr, nullptr, MtB, nullptr, DK, DK);

    // x2 = x + Q @ M + bp -> bf16 x2b ONLY
    gemm128<false,true,true,true,false,false><<<dim3(8, 64), blk, 0, stream>>>(
        QKVb, 3 * DK, MtB, bp, x, x2b, nullptr, DMODEL, DK);

    // h = relu(x2 @ W1^T + b1) -> bf16 [8192,4096]; 1024 blocks, 2/CU
    gemm256x128<true,true><<<1024, blk, 0, stream>>>(
        x2b, DMODEL, W1b, DMODEL, b1, Hb, 0, DFF, DMODEL, 1024, DFF / 128);

    // FFN2 split-K=2 -> bf16 partials P0,P1; 512 blocks, 2/CU
    gemm256x128<false,false><<<512, blk, 0, stream>>>(
        Hb, DFF, W2b, DFF, nullptr, P0b,
        (long)MROWS * DMODEL, DMODEL, DFF / 2, 256, DMODEL / 128);

    // y = x2b + P0 + P1 + b2 (write-only fp32 d_out)
    ffn2_reduce2<<<2048, blk, 0, stream>>>(out, x2b, P0b, P1b, b2,
                                           MROWS * DMODEL / 8);
}